// Round 10
// baseline (295.570 us; speedup 1.0000x reference)
//
#include <hip/hip_runtime.h>
#include <hip/hip_bf16.h>
#include <stdint.h>

// Problem constants: B=4, T=4096, L=4096, H=1024
#define BB 4
#define TT 4096
#define LL 4096
#define HH 1024

typedef __bf16 bf16x8 __attribute__((ext_vector_type(8)));
typedef float f32x4 __attribute__((ext_vector_type(4)));
typedef unsigned short us8v __attribute__((ext_vector_type(8)));
typedef unsigned short us;

__device__ __forceinline__ unsigned short f2b(float f) {
    unsigned u = __builtin_bit_cast(unsigned, f);
    unsigned r = (u + 0x7FFFu + ((u >> 16) & 1u)) >> 16;
    return (unsigned short)r;
}
__device__ __forceinline__ float b2f(unsigned short u) {
    unsigned x = ((unsigned)u) << 16;
    return __builtin_bit_cast(float, x);
}

__device__ __forceinline__ void gload_lds16(const void* g, void* l) {
    __builtin_amdgcn_global_load_lds(
        (const __attribute__((address_space(1))) void*)(uintptr_t)g,
        (__attribute__((address_space(3))) void*)(uintptr_t)l,
        16, 0, 0);
}

// ---------------- f32 -> bf16 conversion ----------------
__global__ __launch_bounds__(256) void cvt_f32_bf16_k(const float4* __restrict__ src,
                                                      ushort4* __restrict__ dst, int n4) {
    int i = blockIdx.x * 256 + threadIdx.x;
    if (i >= n4) return;
    float4 v = src[i];
    ushort4 o;
    o.x = f2b(v.x); o.y = f2b(v.y); o.z = f2b(v.z); o.w = f2b(v.w);
    dst[i] = o;
}

// ---------------- six f32 [1024][1024] -> bf16 transposes, one launch ----------------
struct TrArgs { const float* s[6]; unsigned short* d[6]; };
__global__ __launch_bounds__(256) void transp6_cvt_k(TrArgs ta) {
    __shared__ float tile[32][33];
    const int z = blockIdx.z;
    const float* src = ta.s[z];
    unsigned short* dst = ta.d[z];
    const int lx = threadIdx.x & 31, ly = threadIdx.x >> 5;
    const int R = blockIdx.y * 32, C = blockIdx.x * 32;
#pragma unroll
    for (int rr = 0; rr < 4; rr++)
        tile[ly + rr * 8][lx] = src[(size_t)(R + ly + rr * 8) * HH + C + lx];
    __syncthreads();
#pragma unroll
    for (int rr = 0; rr < 4; rr++)
        dst[(size_t)(C + ly + rr * 8) * HH + R + lx] = f2b(tile[lx][ly + rr * 8]);
}

// ---------------- four 1024^3 weight-fold GEMMs in one launch ------------------------
struct FoldArgs { const us* A[4]; const us* B[4]; us* D[4]; };
__global__ __launch_bounds__(256) void gemm_fold4(FoldArgs fa) {
    const int K = 1024;
    __shared__ unsigned short ldsA[128 * 64];
    __shared__ unsigned short ldsB[128 * 64];

    const int z = blockIdx.z;
    const us* A = fa.A[z];
    const us* Bw = fa.B[z];
    us* dst = fa.D[z];

    const int tid = threadIdx.x;
    const int wave = tid >> 6, lane = tid & 63;
    const int m0 = blockIdx.y * 128, n0 = blockIdx.x * 128;
    const int wr = wave >> 1, wc = wave & 1;

    f32x4 acc[4][4];
#pragma unroll
    for (int m = 0; m < 4; m++)
#pragma unroll
        for (int n = 0; n < 4; n++) acc[m][n] = (f32x4)(0.0f);

    const us* Ab = A + (size_t)m0 * K;
    const us* Bb = Bw + (size_t)n0 * K;
    const int rbase = tid >> 3;
    const int col0 = (((tid & 7) ^ (rbase & 7)) << 3);

    for (int k0 = 0; k0 < K; k0 += 64) {
#pragma unroll
        for (int r = 0; r < 4; r++) {
            const int row = r * 32 + rbase;
            gload_lds16(Ab + (size_t)row * K + k0 + col0, &ldsA[r * 2048 + wave * 512]);
            gload_lds16(Bb + (size_t)row * K + k0 + col0, &ldsB[r * 2048 + wave * 512]);
        }
        __syncthreads();

        const int lr = lane & 15, hi = lane >> 4;
        const int sw = (lr & 7) << 4;
        const int c0 = ((hi * 16) ^ sw) >> 1;
        const int c1 = ((64 + hi * 16) ^ sw) >> 1;
        bf16x8 a0[4], a1[4], b0[4], b1[4];
#pragma unroll
        for (int m = 0; m < 4; m++) {
            const int row = (wr * 64 + m * 16 + lr) * 64;
            a0[m] = *reinterpret_cast<const bf16x8*>(&ldsA[row + c0]);
            a1[m] = *reinterpret_cast<const bf16x8*>(&ldsA[row + c1]);
        }
#pragma unroll
        for (int n = 0; n < 4; n++) {
            const int row = (wc * 64 + n * 16 + lr) * 64;
            b0[n] = *reinterpret_cast<const bf16x8*>(&ldsB[row + c0]);
            b1[n] = *reinterpret_cast<const bf16x8*>(&ldsB[row + c1]);
        }
#pragma unroll
        for (int m = 0; m < 4; m++)
#pragma unroll
            for (int n = 0; n < 4; n++)
                acc[m][n] = __builtin_amdgcn_mfma_f32_16x16x32_bf16(a0[m], b0[n], acc[m][n], 0, 0, 0);
#pragma unroll
        for (int m = 0; m < 4; m++)
#pragma unroll
            for (int n = 0; n < 4; n++)
                acc[m][n] = __builtin_amdgcn_mfma_f32_16x16x32_bf16(a1[m], b1[n], acc[m][n], 0, 0, 0);
        __syncthreads();
    }

    const int cc = lane & 15, cr = (lane >> 4) * 4;
#pragma unroll
    for (int m = 0; m < 4; m++)
#pragma unroll
        for (int n = 0; n < 4; n++)
#pragma unroll
            for (int r = 0; r < 4; r++) {
                const int row = m0 + wr * 64 + m * 16 + cr + r;
                const int col = n0 + wc * 64 + n * 16 + cc;
                dst[(size_t)row * 1024 + col] = f2b(acc[m][n][r]);
            }
}

// ---------------- 256x256 GEMM (R5/R8 structure, 16x16x32, 0-conflict swizzle) -------
__device__ __forceinline__ void mfma32(const bf16x8 a[8], const bf16x8 b[4], f32x4 acc[8][4]) {
    __builtin_amdgcn_s_setprio(1);
#pragma unroll
    for (int m = 0; m < 8; m++)
#pragma unroll
        for (int n = 0; n < 4; n++)
            acc[m][n] = __builtin_amdgcn_mfma_f32_16x16x32_bf16(a[m], b[n], acc[m][n], 0, 0, 0);
    __builtin_amdgcn_s_setprio(0);
}

#define STAGE2(chunk, src, kcol) \
    { _Pragma("unroll") for (int r_ = 0; r_ < 2; r_++) \
        gload_lds16((src) + (size_t)srow[r_] * K + (kcol) + scol[r_], (chunk) + r_ * 4096 + wave * 512); }

#define RD_A8(cA) \
    { _Pragma("unroll") for (int m_ = 0; m_ < 8; m_++) \
        a[m_] = *reinterpret_cast<const bf16x8*>((cA) + offA + m_ * 512); }

#define RD_B4(cB) \
    { _Pragma("unroll") for (int n_ = 0; n_ < 4; n_++) \
        b[n_] = *reinterpret_cast<const bf16x8*>((cB) + offB + n_ * 512); }

#define BAR __builtin_amdgcn_s_barrier()
#define SB0 __builtin_amdgcn_sched_barrier(0)
#define VMW4 asm volatile("s_waitcnt vmcnt(4)" ::: "memory")
#define VMW0 asm volatile("s_waitcnt vmcnt(0)" ::: "memory")
#define NOWAIT

#define HALF(cA, cB, nA, nB, kn, STG, WAIT)                  \
  {                                                           \
    RD_A8(cA); RD_B4(cB);                                     \
    if (STG) { STAGE2(nA, Ablk, (kn)); STAGE2(nB, Bblk, (kn)); } \
    mfma32(a, b, acc);                                        \
    WAIT;                                                     \
    BAR; SB0;                                                 \
  }

__global__ __launch_bounds__(512, 2) void gemm256(const us* __restrict__ A,
                                                  const us* __restrict__ Bw,
                                                  us* __restrict__ C,
                                                  int M, int N, int K, int gx) {
    __shared__ us lds[65536];   // 128 KB

    const int nwg = gridDim.x;
    const int bid = blockIdx.x;
    const int swz = (bid & 7) * (nwg >> 3) + (bid >> 3);   // grids multiple of 8
    const int bx = swz % gx, by = swz / gx;
    const int m0 = by * 256, n0 = bx * 256;

    const int tid = threadIdx.x;
    const int wave = tid >> 6, lane = tid & 63;
    const int wr = wave >> 2, wc = wave & 3;
    const int lr = lane & 15, hi = lane >> 4;

    int srow[2], scol[2];
#pragma unroll
    for (int r = 0; r < 2; r++) {
        const int q = r * 64 + (tid >> 3);
        const int s = (tid & 7) ^ (q & 7);
        srow[r] = 2 * q + (s >> 2);
        scol[r] = (s & 3) * 8;
    }
    const us* Ablk = A + (size_t)m0 * K;
    const us* Bblk = Bw + (size_t)n0 * K;

    const int rA = wr * 128 + lr;
    const int offA = (rA >> 1) * 64 + (((((rA & 1) << 2) + hi) ^ ((rA >> 1) & 7)) << 3);
    const int rB = wc * 64 + lr;
    const int offB = (rB >> 1) * 64 + (((((rB & 1) << 2) + hi) ^ ((rB >> 1) & 7)) << 3);

    f32x4 acc[8][4];
#pragma unroll
    for (int m = 0; m < 8; m++)
#pragma unroll
        for (int n = 0; n < 4; n++) acc[m][n] = (f32x4)(0.0f);

    us* cA0 = lds;          us* cA1 = lds + 8192;
    us* cB0 = lds + 16384;  us* cB1 = lds + 24576;
    us* nA0 = lds + 32768;  us* nA1 = lds + 40960;
    us* nB0 = lds + 49152;  us* nB1 = lds + 57344;

    bf16x8 a[8], b[4];

    STAGE2(cA0, Ablk, 0);
    STAGE2(cB0, Bblk, 0);
    STAGE2(cA1, Ablk, 32);
    STAGE2(cB1, Bblk, 32);
    VMW4;
    BAR; SB0;

    const int NT = K >> 6;
    for (int t = 0; t < NT - 1; ++t) {
        const int kn = (t + 1) << 6;
        HALF(cA0, cB0, nA0, nB0, kn, true, VMW4);
        HALF(cA1, cB1, nA1, nB1, kn + 32, true, VMW4);
        us* s0 = cA0; cA0 = nA0; nA0 = s0;
        us* s1 = cA1; cA1 = nA1; nA1 = s1;
        us* s2 = cB0; cB0 = nB0; nB0 = s2;
        us* s3 = cB1; cB1 = nB1; nB1 = s3;
    }
    HALF(cA0, cB0, nA0, nB0, 0, false, VMW0);
    HALF(cA1, cB1, nA1, nB1, 0, false, NOWAIT);

    const int crow0 = m0 + wr * 128 + hi * 4;
    const int ccol0 = n0 + wc * 64 + lr;
#pragma unroll
    for (int mi = 0; mi < 8; mi++)
#pragma unroll
        for (int ni = 0; ni < 4; ni++)
#pragma unroll
            for (int rr = 0; rr < 4; rr++)
                C[(size_t)(crow0 + mi * 16 + rr) * N + ccol0 + ni * 16] = f2b(acc[mi][ni][rr]);
}

// ---------------- windowed 3-way gated attention, hs-direct ---------------------------
// HS: [nb*T][1024] f32 (nontemporal; touched once)   KV: [nb*L][4096] bf16 (cached)
// out: f32 (nontemporal store; touched once). One wave per t; 16 channels/lane.
// Dot partials hoisted; all 6 wave reductions interleaved (6x ILP on the shfl chains).
__global__ __launch_bounds__(256) void attn_k(const float* __restrict__ HS,
                                              const unsigned short* __restrict__ KV,
                                              const int* __restrict__ adv_ids,
                                              const int* __restrict__ ptr_ids,
                                              const float* __restrict__ council,
                                              const float* __restrict__ gain_p,
                                              float* __restrict__ out) {
    const int wave = threadIdx.x >> 6, lane = threadIdx.x & 63;
    const int gid = blockIdx.x * 4 + wave;
    const int b = gid >> 12, t = gid & 4095;

    const int p = ptr_ids[b * TT + t];
    int idx[3];
#pragma unroll
    for (int w = 0; w < 3; w++) {
        int v = p + w;
        idx[w] = v < (LL - 1) ? v : (LL - 1);
        if (idx[w] < 0) idx[w] = 0;
    }
    const int rel = adv_ids[b * LL + idx[0]];

    // query = raw hidden state row (f32, streamed — keep out of caches)
    float qf[16];
    {
        const f32x4* hrow = reinterpret_cast<const f32x4*>(HS + (size_t)gid * 1024 + lane * 16);
#pragma unroll
        for (int v = 0; v < 4; v++) {
            f32x4 x = __builtin_nontemporal_load(hrow + v);
            qf[v * 4 + 0] = x[0]; qf[v * 4 + 1] = x[1]; qf[v * 4 + 2] = x[2]; qf[v * 4 + 3] = x[3];
        }
    }

    // hoisted loads + dot partials (no reductions yet)
    float dj[3], di[3];
    us8v vj[3][2], vi[3][2];
#pragma unroll
    for (int w = 0; w < 3; w++) {
        const unsigned short* kvrow = KV + (size_t)(b * LL + idx[w]) * 4096 + lane * 16;
        us8v kj0 = *reinterpret_cast<const us8v*>(kvrow);
        us8v kj1 = *reinterpret_cast<const us8v*>(kvrow + 8);
        vj[w][0] = *reinterpret_cast<const us8v*>(kvrow + 1024);
        vj[w][1] = *reinterpret_cast<const us8v*>(kvrow + 1032);
        us8v ki0 = *reinterpret_cast<const us8v*>(kvrow + 2048);
        us8v ki1 = *reinterpret_cast<const us8v*>(kvrow + 2056);
        vi[w][0] = *reinterpret_cast<const us8v*>(kvrow + 3072);
        vi[w][1] = *reinterpret_cast<const us8v*>(kvrow + 3080);

        float a = 0.f, c = 0.f;
#pragma unroll
        for (int e = 0; e < 8; e++) {
            a += qf[e] * b2f(kj0[e]) + qf[8 + e] * b2f(kj1[e]);
            c += qf[e] * b2f(ki0[e]) + qf[8 + e] * b2f(ki1[e]);
        }
        dj[w] = a;
        di[w] = c;
    }

    // interleaved 6-way butterfly reduction over 64 lanes
#pragma unroll
    for (int off = 32; off > 0; off >>= 1) {
#pragma unroll
        for (int w = 0; w < 3; w++) {
            dj[w] += __shfl_xor(dj[w], off, 64);
            di[w] += __shfl_xor(di[w], off, 64);
        }
    }
    float sj[3], si[3];
#pragma unroll
    for (int w = 0; w < 3; w++) {
        sj[w] = dj[w] * 0.03125f;   // 1/sqrt(1024)
        si[w] = di[w] * 0.03125f;
    }

    const float l1 = sj[1], l2 = sj[2];
    float lf;
    switch (rel) {
        case 0: lf = l1 + l2; break;
        case 1: lf = fmaxf(l1, l2); break;
        case 2: lf = -l1; break;
        case 3: lf = fmaxf(-l1, l2); break;
        case 4: lf = fabsf(l1 - l2); break;
        default: lf = sj[0]; break;
    }

    float mj = fmaxf(lf, fmaxf(l1, l2));
    float ej0 = expf(lf - mj), ej1 = expf(l1 - mj), ej2 = expf(l2 - mj);
    float invj = 1.0f / (ej0 + ej1 + ej2);
    float aj0 = ej0 * invj, aj1 = ej1 * invj, aj2 = ej2 * invj;

    float mi2 = fmaxf(si[0], fmaxf(si[1], si[2]));
    float ei0 = expf(si[0] - mi2), ei1 = expf(si[1] - mi2), ei2 = expf(si[2] - mi2);
    float invi = 1.0f / (ei0 + ei1 + ei2);
    float ai0 = ei0 * invi, ai1 = ei1 * invi, ai2 = ei2 * invi;

    float c0 = council[0], c1 = council[1];
    float cm = fmaxf(c0, c1);
    float w0 = expf(c0 - cm), w1 = expf(c1 - cm);
    float wsum = 1.0f / (w0 + w1);
    w0 *= wsum; w1 *= wsum;
    const float g = *gain_p;

    float* dst = out + (size_t)gid * 1024 + lane * 16;
#pragma unroll
    for (int h = 0; h < 2; h++) {
        f32x4 o0, o1;
#pragma unroll
        for (int e = 0; e < 8; e++) {
            float cj = aj0 * b2f(vj[0][h][e]) + aj1 * b2f(vj[1][h][e]) + aj2 * b2f(vj[2][h][e]);
            float ci = ai0 * b2f(vi[0][h][e]) + ai1 * b2f(vi[1][h][e]) + ai2 * b2f(vi[2][h][e]);
            float val = (w0 * cj + w1 * ci) * g;
            if (e < 4) o0[e] = val; else o1[e - 4] = val;
        }
        f32x4* dv = reinterpret_cast<f32x4*>(dst + h * 8);
        __builtin_nontemporal_store(o0, dv);
        __builtin_nontemporal_store(o1, dv + 1);
    }
}

// ---------------- launch ----------------
extern "C" void kernel_launch(void* const* d_in, const int* in_sizes, int n_in,
                              void* d_out, int out_size, void* d_ws, size_t ws_size,
                              hipStream_t stream) {
    const float* hs      = (const float*)d_in[0];
    const float* adv     = (const float*)d_in[1];
    const int*   adv_ids = (const int*)d_in[2];
    const int*   ptr_ids = (const int*)d_in[3];
    const float* Wqj = (const float*)d_in[4];
    const float* Wkj = (const float*)d_in[5];
    const float* Wvj = (const float*)d_in[6];
    const float* Wqi = (const float*)d_in[7];
    const float* Wki = (const float*)d_in[8];
    const float* Wvi = (const float*)d_in[9];
    const float* Wout = (const float*)d_in[10];
    const float* gain = (const float*)d_in[11];
    const float* council = (const float*)d_in[12];
    float* out = (float*)d_out;

    const size_t WN  = (size_t)HH * HH;
    const size_t NHb = (size_t)TT * HH;
    dim3 blk(256);

    auto cvt = [&](const float* s, unsigned short* d, size_t n) {
        int n4 = (int)(n / 4);
        cvt_f32_bf16_k<<<dim3(n4 / 256), blk, 0, stream>>>((const float4*)s, (ushort4*)d, n4);
    };

    // ---- weight buffers: Wkv pack 8MB + WoutB 2MB + 6 transposes 12MB = 22 MB ----
    char* ws = (char*)d_ws;
    unsigned short* Wkv   = (unsigned short*)ws;  ws += WN * 4 * 2;   // [Mj|Vj2|Mi|Vi2]
    unsigned short* WoutB = (unsigned short*)ws;  ws += WN * 2;
    unsigned short* WT    = (unsigned short*)ws;  ws += WN * 6 * 2;   // qjT kjT qiT kiT vjT viT

    cvt(Wout, WoutB, WN);
    TrArgs ta;
    ta.s[0] = Wqj; ta.d[0] = WT;
    ta.s[1] = Wkj; ta.d[1] = WT + WN;
    ta.s[2] = Wqi; ta.d[2] = WT + 2 * WN;
    ta.s[3] = Wki; ta.d[3] = WT + 3 * WN;
    ta.s[4] = Wvj; ta.d[4] = WT + 4 * WN;
    ta.s[5] = Wvi; ta.d[5] = WT + 5 * WN;
    transp6_cvt_k<<<dim3(32, 32, 6), blk, 0, stream>>>(ta);

    // folds: Mj = WqjT @ WkjT^T, Vj2 = Wout @ WvjT^T, Mi, Vi2  (all 1024^3)
    FoldArgs fa;
    fa.A[0] = WT;          fa.B[0] = WT + WN;     fa.D[0] = Wkv;            // Mj
    fa.A[1] = WoutB;       fa.B[1] = WT + 4 * WN; fa.D[1] = Wkv + WN;       // Vj2
    fa.A[2] = WT + 2 * WN; fa.B[2] = WT + 3 * WN; fa.D[2] = Wkv + 2 * WN;   // Mi
    fa.A[3] = WoutB;       fa.B[3] = WT + 5 * WN; fa.D[3] = Wkv + 3 * WN;   // Vi2
    gemm_fold4<<<dim3(8, 8, 4), blk, 0, stream>>>(fa);

    const size_t full_need = (size_t)(24 * 1024 * 1024) + (NHb * BB) * 2
                           + (size_t)16384 * 4096 * 2;   // advb + KVb ≈ 184 MB

    if (ws_size >= full_need) {
        unsigned short* advb = (unsigned short*)ws;  ws += NHb * BB * 2;
        unsigned short* KVb  = (unsigned short*)ws;

        cvt(adv, advb, NHb * BB);
        gemm256<<<dim3(16 * 64), dim3(512), 0, stream>>>(advb, Wkv, KVb, 16384, 4096, 1024, 16);
        attn_k<<<dim3((BB * TT) / 4), blk, 0, stream>>>(hs, KVb, adv_ids, ptr_ids,
                                                        council, gain, out);
    } else {
        unsigned short* advb = (unsigned short*)ws;  ws += NHb * 2;
        unsigned short* KVb  = (unsigned short*)ws;

        for (int b = 0; b < BB; b++) {
            cvt(adv + (size_t)b * NHb, advb, NHb);
            gemm256<<<dim3(16 * 16), dim3(512), 0, stream>>>(advb, Wkv, KVb, LL, 4096, 1024, 16);
            attn_k<<<dim3(TT / 4), blk, 0, stream>>>(hs + (size_t)b * NHb, KVb,
                                                     adv_ids + b * LL, ptr_ids + b * TT,
                                                     council, gain, out + (size_t)b * NHb);
        }
    }
}

// Round 11
// 268.354 us; speedup vs baseline: 1.1014x; 1.1014x over previous
//
#include <hip/hip_runtime.h>
#include <hip/hip_bf16.h>
#include <stdint.h>

// Problem constants: B=4, T=4096, L=4096, H=1024
#define BB 4
#define TT 4096
#define LL 4096
#define HH 1024

typedef __bf16 bf16x8 __attribute__((ext_vector_type(8)));
typedef float f32x4 __attribute__((ext_vector_type(4)));
typedef unsigned short us8v __attribute__((ext_vector_type(8)));
typedef unsigned short us;

__device__ __forceinline__ unsigned short f2b(float f) {
    unsigned u = __builtin_bit_cast(unsigned, f);
    unsigned r = (u + 0x7FFFu + ((u >> 16) & 1u)) >> 16;
    return (unsigned short)r;
}
__device__ __forceinline__ float b2f(unsigned short u) {
    unsigned x = ((unsigned)u) << 16;
    return __builtin_bit_cast(float, x);
}

__device__ __forceinline__ void gload_lds16(const void* g, void* l) {
    __builtin_amdgcn_global_load_lds(
        (const __attribute__((address_space(1))) void*)(uintptr_t)g,
        (__attribute__((address_space(3))) void*)(uintptr_t)l,
        16, 0, 0);
}

// ---------------- f32 -> bf16 conversion ----------------
__global__ __launch_bounds__(256) void cvt_f32_bf16_k(const float4* __restrict__ src,
                                                      ushort4* __restrict__ dst, int n4) {
    int i = blockIdx.x * 256 + threadIdx.x;
    if (i >= n4) return;
    float4 v = src[i];
    ushort4 o;
    o.x = f2b(v.x); o.y = f2b(v.y); o.z = f2b(v.z); o.w = f2b(v.w);
    dst[i] = o;
}

// ---------------- six f32 [1024][1024] -> bf16 transposes, one launch ----------------
struct TrArgs { const float* s[6]; unsigned short* d[6]; };
__global__ __launch_bounds__(256) void transp6_cvt_k(TrArgs ta) {
    __shared__ float tile[32][33];
    const int z = blockIdx.z;
    const float* src = ta.s[z];
    unsigned short* dst = ta.d[z];
    const int lx = threadIdx.x & 31, ly = threadIdx.x >> 5;
    const int R = blockIdx.y * 32, C = blockIdx.x * 32;
#pragma unroll
    for (int rr = 0; rr < 4; rr++)
        tile[ly + rr * 8][lx] = src[(size_t)(R + ly + rr * 8) * HH + C + lx];
    __syncthreads();
#pragma unroll
    for (int rr = 0; rr < 4; rr++)
        dst[(size_t)(C + ly + rr * 8) * HH + R + lx] = f2b(tile[lx][ly + rr * 8]);
}

// ---------------- four 1024^3 weight-fold GEMMs in one launch ------------------------
struct FoldArgs { const us* A[4]; const us* B[4]; us* D[4]; };
__global__ __launch_bounds__(256) void gemm_fold4(FoldArgs fa) {
    const int K = 1024;
    __shared__ unsigned short ldsA[128 * 64];
    __shared__ unsigned short ldsB[128 * 64];

    const int z = blockIdx.z;
    const us* A = fa.A[z];
    const us* Bw = fa.B[z];
    us* dst = fa.D[z];

    const int tid = threadIdx.x;
    const int wave = tid >> 6, lane = tid & 63;
    const int m0 = blockIdx.y * 128, n0 = blockIdx.x * 128;
    const int wr = wave >> 1, wc = wave & 1;

    f32x4 acc[4][4];
#pragma unroll
    for (int m = 0; m < 4; m++)
#pragma unroll
        for (int n = 0; n < 4; n++) acc[m][n] = (f32x4)(0.0f);

    const us* Ab = A + (size_t)m0 * K;
    const us* Bb = Bw + (size_t)n0 * K;
    const int rbase = tid >> 3;
    const int col0 = (((tid & 7) ^ (rbase & 7)) << 3);

    for (int k0 = 0; k0 < K; k0 += 64) {
#pragma unroll
        for (int r = 0; r < 4; r++) {
            const int row = r * 32 + rbase;
            gload_lds16(Ab + (size_t)row * K + k0 + col0, &ldsA[r * 2048 + wave * 512]);
            gload_lds16(Bb + (size_t)row * K + k0 + col0, &ldsB[r * 2048 + wave * 512]);
        }
        __syncthreads();

        const int lr = lane & 15, hi = lane >> 4;
        const int sw = (lr & 7) << 4;
        const int c0 = ((hi * 16) ^ sw) >> 1;
        const int c1 = ((64 + hi * 16) ^ sw) >> 1;
        bf16x8 a0[4], a1[4], b0[4], b1[4];
#pragma unroll
        for (int m = 0; m < 4; m++) {
            const int row = (wr * 64 + m * 16 + lr) * 64;
            a0[m] = *reinterpret_cast<const bf16x8*>(&ldsA[row + c0]);
            a1[m] = *reinterpret_cast<const bf16x8*>(&ldsA[row + c1]);
        }
#pragma unroll
        for (int n = 0; n < 4; n++) {
            const int row = (wc * 64 + n * 16 + lr) * 64;
            b0[n] = *reinterpret_cast<const bf16x8*>(&ldsB[row + c0]);
            b1[n] = *reinterpret_cast<const bf16x8*>(&ldsB[row + c1]);
        }
#pragma unroll
        for (int m = 0; m < 4; m++)
#pragma unroll
            for (int n = 0; n < 4; n++)
                acc[m][n] = __builtin_amdgcn_mfma_f32_16x16x32_bf16(a0[m], b0[n], acc[m][n], 0, 0, 0);
#pragma unroll
        for (int m = 0; m < 4; m++)
#pragma unroll
            for (int n = 0; n < 4; n++)
                acc[m][n] = __builtin_amdgcn_mfma_f32_16x16x32_bf16(a1[m], b1[n], acc[m][n], 0, 0, 0);
        __syncthreads();
    }

    const int cc = lane & 15, cr = (lane >> 4) * 4;
#pragma unroll
    for (int m = 0; m < 4; m++)
#pragma unroll
        for (int n = 0; n < 4; n++)
#pragma unroll
            for (int r = 0; r < 4; r++) {
                const int row = m0 + wr * 64 + m * 16 + cr + r;
                const int col = n0 + wc * 64 + n * 16 + cc;
                dst[(size_t)row * 1024 + col] = f2b(acc[m][n][r]);
            }
}

// ---------------- 256x256 GEMM (R5/R8 structure, 16x16x32, 0-conflict swizzle) -------
__device__ __forceinline__ void mfma32(const bf16x8 a[8], const bf16x8 b[4], f32x4 acc[8][4]) {
    __builtin_amdgcn_s_setprio(1);
#pragma unroll
    for (int m = 0; m < 8; m++)
#pragma unroll
        for (int n = 0; n < 4; n++)
            acc[m][n] = __builtin_amdgcn_mfma_f32_16x16x32_bf16(a[m], b[n], acc[m][n], 0, 0, 0);
    __builtin_amdgcn_s_setprio(0);
}

#define STAGE2(chunk, src, kcol) \
    { _Pragma("unroll") for (int r_ = 0; r_ < 2; r_++) \
        gload_lds16((src) + (size_t)srow[r_] * K + (kcol) + scol[r_], (chunk) + r_ * 4096 + wave * 512); }

#define RD_A8(cA) \
    { _Pragma("unroll") for (int m_ = 0; m_ < 8; m_++) \
        a[m_] = *reinterpret_cast<const bf16x8*>((cA) + offA + m_ * 512); }

#define RD_B4(cB) \
    { _Pragma("unroll") for (int n_ = 0; n_ < 4; n_++) \
        b[n_] = *reinterpret_cast<const bf16x8*>((cB) + offB + n_ * 512); }

#define BAR __builtin_amdgcn_s_barrier()
#define SB0 __builtin_amdgcn_sched_barrier(0)
#define VMW4 asm volatile("s_waitcnt vmcnt(4)" ::: "memory")
#define VMW0 asm volatile("s_waitcnt vmcnt(0)" ::: "memory")
#define NOWAIT

#define HALF(cA, cB, nA, nB, kn, STG, WAIT)                  \
  {                                                           \
    RD_A8(cA); RD_B4(cB);                                     \
    if (STG) { STAGE2(nA, Ablk, (kn)); STAGE2(nB, Bblk, (kn)); } \
    mfma32(a, b, acc);                                        \
    WAIT;                                                     \
    BAR; SB0;                                                 \
  }

__global__ __launch_bounds__(512, 2) void gemm256(const us* __restrict__ A,
                                                  const us* __restrict__ Bw,
                                                  us* __restrict__ C,
                                                  int M, int N, int K, int gx) {
    __shared__ us lds[65536];   // 128 KB

    const int nwg = gridDim.x;
    const int bid = blockIdx.x;
    const int swz = (bid & 7) * (nwg >> 3) + (bid >> 3);   // grids multiple of 8
    const int bx = swz % gx, by = swz / gx;
    const int m0 = by * 256, n0 = bx * 256;

    const int tid = threadIdx.x;
    const int wave = tid >> 6, lane = tid & 63;
    const int wr = wave >> 2, wc = wave & 3;
    const int lr = lane & 15, hi = lane >> 4;

    int srow[2], scol[2];
#pragma unroll
    for (int r = 0; r < 2; r++) {
        const int q = r * 64 + (tid >> 3);
        const int s = (tid & 7) ^ (q & 7);
        srow[r] = 2 * q + (s >> 2);
        scol[r] = (s & 3) * 8;
    }
    const us* Ablk = A + (size_t)m0 * K;
    const us* Bblk = Bw + (size_t)n0 * K;

    const int rA = wr * 128 + lr;
    const int offA = (rA >> 1) * 64 + (((((rA & 1) << 2) + hi) ^ ((rA >> 1) & 7)) << 3);
    const int rB = wc * 64 + lr;
    const int offB = (rB >> 1) * 64 + (((((rB & 1) << 2) + hi) ^ ((rB >> 1) & 7)) << 3);

    f32x4 acc[8][4];
#pragma unroll
    for (int m = 0; m < 8; m++)
#pragma unroll
        for (int n = 0; n < 4; n++) acc[m][n] = (f32x4)(0.0f);

    us* cA0 = lds;          us* cA1 = lds + 8192;
    us* cB0 = lds + 16384;  us* cB1 = lds + 24576;
    us* nA0 = lds + 32768;  us* nA1 = lds + 40960;
    us* nB0 = lds + 49152;  us* nB1 = lds + 57344;

    bf16x8 a[8], b[4];

    STAGE2(cA0, Ablk, 0);
    STAGE2(cB0, Bblk, 0);
    STAGE2(cA1, Ablk, 32);
    STAGE2(cB1, Bblk, 32);
    VMW4;
    BAR; SB0;

    const int NT = K >> 6;
    for (int t = 0; t < NT - 1; ++t) {
        const int kn = (t + 1) << 6;
        HALF(cA0, cB0, nA0, nB0, kn, true, VMW4);
        HALF(cA1, cB1, nA1, nB1, kn + 32, true, VMW4);
        us* s0 = cA0; cA0 = nA0; nA0 = s0;
        us* s1 = cA1; cA1 = nA1; nA1 = s1;
        us* s2 = cB0; cB0 = nB0; nB0 = s2;
        us* s3 = cB1; cB1 = nB1; nB1 = s3;
    }
    HALF(cA0, cB0, nA0, nB0, 0, false, VMW0);
    HALF(cA1, cB1, nA1, nB1, 0, false, NOWAIT);

    const int crow0 = m0 + wr * 128 + hi * 4;
    const int ccol0 = n0 + wc * 64 + lr;
#pragma unroll
    for (int mi = 0; mi < 8; mi++)
#pragma unroll
        for (int ni = 0; ni < 4; ni++)
#pragma unroll
            for (int rr = 0; rr < 4; rr++)
                C[(size_t)(crow0 + mi * 16 + rr) * N + ccol0 + ni * 16] = f2b(acc[mi][ni][rr]);
}

// ---------------- windowed 3-way gated attention, hs-direct ---------------------------
// HS: [nb*T][1024] f32   KV: [nb*L][4096] bf16 (kj'|vj'|ki'|vi')   out: f32 (x gain)
// One wave per t; 16 channels/lane; dot partials hoisted, 6 reductions interleaved.
__global__ __launch_bounds__(256) void attn_k(const float* __restrict__ HS,
                                              const unsigned short* __restrict__ KV,
                                              const int* __restrict__ adv_ids,
                                              const int* __restrict__ ptr_ids,
                                              const float* __restrict__ council,
                                              const float* __restrict__ gain_p,
                                              float* __restrict__ out) {
    const int wave = threadIdx.x >> 6, lane = threadIdx.x & 63;
    const int gid = blockIdx.x * 4 + wave;
    const int b = gid >> 12, t = gid & 4095;

    const int p = ptr_ids[b * TT + t];
    int idx[3];
#pragma unroll
    for (int w = 0; w < 3; w++) {
        int v = p + w;
        idx[w] = v < (LL - 1) ? v : (LL - 1);
        if (idx[w] < 0) idx[w] = 0;
    }
    const int rel = adv_ids[b * LL + idx[0]];

    // query = raw hidden state row (f32)
    float qf[16];
    {
        const f32x4* hrow = reinterpret_cast<const f32x4*>(HS + (size_t)gid * 1024 + lane * 16);
#pragma unroll
        for (int v = 0; v < 4; v++) {
            f32x4 x = hrow[v];
            qf[v * 4 + 0] = x[0]; qf[v * 4 + 1] = x[1]; qf[v * 4 + 2] = x[2]; qf[v * 4 + 3] = x[3];
        }
    }

    // hoisted loads + dot partials (no reductions yet)
    float dj[3], di[3];
    us8v vj[3][2], vi[3][2];
#pragma unroll
    for (int w = 0; w < 3; w++) {
        const unsigned short* kvrow = KV + (size_t)(b * LL + idx[w]) * 4096 + lane * 16;
        us8v kj0 = *reinterpret_cast<const us8v*>(kvrow);
        us8v kj1 = *reinterpret_cast<const us8v*>(kvrow + 8);
        vj[w][0] = *reinterpret_cast<const us8v*>(kvrow + 1024);
        vj[w][1] = *reinterpret_cast<const us8v*>(kvrow + 1032);
        us8v ki0 = *reinterpret_cast<const us8v*>(kvrow + 2048);
        us8v ki1 = *reinterpret_cast<const us8v*>(kvrow + 2056);
        vi[w][0] = *reinterpret_cast<const us8v*>(kvrow + 3072);
        vi[w][1] = *reinterpret_cast<const us8v*>(kvrow + 3080);

        float a = 0.f, c = 0.f;
#pragma unroll
        for (int e = 0; e < 8; e++) {
            a += qf[e] * b2f(kj0[e]) + qf[8 + e] * b2f(kj1[e]);
            c += qf[e] * b2f(ki0[e]) + qf[8 + e] * b2f(ki1[e]);
        }
        dj[w] = a;
        di[w] = c;
    }

    // interleaved 6-way butterfly reduction over 64 lanes
#pragma unroll
    for (int off = 32; off > 0; off >>= 1) {
#pragma unroll
        for (int w = 0; w < 3; w++) {
            dj[w] += __shfl_xor(dj[w], off, 64);
            di[w] += __shfl_xor(di[w], off, 64);
        }
    }
    float sj[3], si[3];
#pragma unroll
    for (int w = 0; w < 3; w++) {
        sj[w] = dj[w] * 0.03125f;   // 1/sqrt(1024)
        si[w] = di[w] * 0.03125f;
    }

    const float l1 = sj[1], l2 = sj[2];
    float lf;
    switch (rel) {
        case 0: lf = l1 + l2; break;
        case 1: lf = fmaxf(l1, l2); break;
        case 2: lf = -l1; break;
        case 3: lf = fmaxf(-l1, l2); break;
        case 4: lf = fabsf(l1 - l2); break;
        default: lf = sj[0]; break;
    }

    float mj = fmaxf(lf, fmaxf(l1, l2));
    float ej0 = expf(lf - mj), ej1 = expf(l1 - mj), ej2 = expf(l2 - mj);
    float invj = 1.0f / (ej0 + ej1 + ej2);
    float aj0 = ej0 * invj, aj1 = ej1 * invj, aj2 = ej2 * invj;

    float mi2 = fmaxf(si[0], fmaxf(si[1], si[2]));
    float ei0 = expf(si[0] - mi2), ei1 = expf(si[1] - mi2), ei2 = expf(si[2] - mi2);
    float invi = 1.0f / (ei0 + ei1 + ei2);
    float ai0 = ei0 * invi, ai1 = ei1 * invi, ai2 = ei2 * invi;

    float c0 = council[0], c1 = council[1];
    float cm = fmaxf(c0, c1);
    float w0 = expf(c0 - cm), w1 = expf(c1 - cm);
    float wsum = 1.0f / (w0 + w1);
    w0 *= wsum; w1 *= wsum;
    const float g = *gain_p;

    float* dst = out + (size_t)gid * 1024 + lane * 16;
#pragma unroll
    for (int h = 0; h < 2; h++) {
        f32x4 o0, o1;
#pragma unroll
        for (int e = 0; e < 8; e++) {
            float cj = aj0 * b2f(vj[0][h][e]) + aj1 * b2f(vj[1][h][e]) + aj2 * b2f(vj[2][h][e]);
            float ci = ai0 * b2f(vi[0][h][e]) + ai1 * b2f(vi[1][h][e]) + ai2 * b2f(vi[2][h][e]);
            float val = (w0 * cj + w1 * ci) * g;
            if (e < 4) o0[e] = val; else o1[e - 4] = val;
        }
        f32x4* dv = reinterpret_cast<f32x4*>(dst + h * 8);
        dv[0] = o0;
        dv[1] = o1;
    }
}

// ---------------- launch ----------------
extern "C" void kernel_launch(void* const* d_in, const int* in_sizes, int n_in,
                              void* d_out, int out_size, void* d_ws, size_t ws_size,
                              hipStream_t stream) {
    const float* hs      = (const float*)d_in[0];
    const float* adv     = (const float*)d_in[1];
    const int*   adv_ids = (const int*)d_in[2];
    const int*   ptr_ids = (const int*)d_in[3];
    const float* Wqj = (const float*)d_in[4];
    const float* Wkj = (const float*)d_in[5];
    const float* Wvj = (const float*)d_in[6];
    const float* Wqi = (const float*)d_in[7];
    const float* Wki = (const float*)d_in[8];
    const float* Wvi = (const float*)d_in[9];
    const float* Wout = (const float*)d_in[10];
    const float* gain = (const float*)d_in[11];
    const float* council = (const float*)d_in[12];
    float* out = (float*)d_out;

    const size_t WN  = (size_t)HH * HH;
    const size_t NHb = (size_t)TT * HH;
    dim3 blk(256);

    auto cvt = [&](const float* s, unsigned short* d, size_t n) {
        int n4 = (int)(n / 4);
        cvt_f32_bf16_k<<<dim3(n4 / 256), blk, 0, stream>>>((const float4*)s, (ushort4*)d, n4);
    };

    // ---- weight buffers: Wkv pack 8MB + WoutB 2MB + 6 transposes 12MB = 22 MB ----
    char* ws = (char*)d_ws;
    unsigned short* Wkv   = (unsigned short*)ws;  ws += WN * 4 * 2;   // [Mj|Vj2|Mi|Vi2]
    unsigned short* WoutB = (unsigned short*)ws;  ws += WN * 2;
    unsigned short* WT    = (unsigned short*)ws;  ws += WN * 6 * 2;   // qjT kjT qiT kiT vjT viT

    cvt(Wout, WoutB, WN);
    TrArgs ta;
    ta.s[0] = Wqj; ta.d[0] = WT;
    ta.s[1] = Wkj; ta.d[1] = WT + WN;
    ta.s[2] = Wqi; ta.d[2] = WT + 2 * WN;
    ta.s[3] = Wki; ta.d[3] = WT + 3 * WN;
    ta.s[4] = Wvj; ta.d[4] = WT + 4 * WN;
    ta.s[5] = Wvi; ta.d[5] = WT + 5 * WN;
    transp6_cvt_k<<<dim3(32, 32, 6), blk, 0, stream>>>(ta);

    // folds: Mj = WqjT @ WkjT^T, Vj2 = Wout @ WvjT^T, Mi, Vi2  (all 1024^3)
    FoldArgs fa;
    fa.A[0] = WT;          fa.B[0] = WT + WN;     fa.D[0] = Wkv;            // Mj
    fa.A[1] = WoutB;       fa.B[1] = WT + 4 * WN; fa.D[1] = Wkv + WN;       // Vj2
    fa.A[2] = WT + 2 * WN; fa.B[2] = WT + 3 * WN; fa.D[2] = Wkv + 2 * WN;   // Mi
    fa.A[3] = WoutB;       fa.B[3] = WT + 5 * WN; fa.D[3] = Wkv + 3 * WN;   // Vi2
    gemm_fold4<<<dim3(8, 8, 4), blk, 0, stream>>>(fa);

    const size_t full_need = (size_t)(24 * 1024 * 1024) + (NHb * BB) * 2
                           + (size_t)16384 * 4096 * 2;   // advb + KVb ≈ 184 MB

    if (ws_size >= full_need) {
        unsigned short* advb = (unsigned short*)ws;  ws += NHb * BB * 2;
        unsigned short* KVb  = (unsigned short*)ws;

        cvt(adv, advb, NHb * BB);
        gemm256<<<dim3(16 * 64), dim3(512), 0, stream>>>(advb, Wkv, KVb, 16384, 4096, 1024, 16);
        attn_k<<<dim3((BB * TT) / 4), blk, 0, stream>>>(hs, KVb, adv_ids, ptr_ids,
                                                        council, gain, out);
    } else {
        unsigned short* advb = (unsigned short*)ws;  ws += NHb * 2;
        unsigned short* KVb  = (unsigned short*)ws;

        for (int b = 0; b < BB; b++) {
            cvt(adv + (size_t)b * NHb, advb, NHb);
            gemm256<<<dim3(16 * 16), dim3(512), 0, stream>>>(advb, Wkv, KVb, LL, 4096, 1024, 16);
            attn_k<<<dim3(TT / 4), blk, 0, stream>>>(hs + (size_t)b * NHb, KVb,
                                                     adv_ids + b * LL, ptr_ids + b * TT,
                                                     council, gain, out + (size_t)b * NHb);
        }
    }
}